// Round 1
// 1964.126 us; speedup vs baseline: 1.0437x; 1.0437x over previous
//
#include <hip/hip_runtime.h>
#include <stdint.h>
#include <algorithm>

#define BATCH 8
#define NPTS 16384
#define NPOINT 1024
#define KNN 32
#define SAMPLE_NUM 10
#define SELN 7
#define SUBSET 29
#define RADIUS 0.2f
#define CAP 2048

// ---------------------------------------------------------------------------
// Host-side threefry2x32 replicating jax.random under the PARTITIONABLE
// implementation (jax_threefry_partitionable defaults True since JAX 0.4.36):
//   key(42) = (0,42)
//   fold_in(key,i)   = tf(key, (c0=0, c1=i))
//   split(folded)[1] = tf(folded, (c0=0, c1=1))
//   random_bits(subkey, 32, (32,)): lane j = tf(subkey, (0, j)), bits = o0^o1
//   permutation      = arange(32) stably sorted by bits ascending
// ---------------------------------------------------------------------------
struct PermTab { unsigned char p[SAMPLE_NUM][SUBSET]; };

static inline uint32_t rotl32h(uint32_t x, int d) { return (x << d) | (x >> (32 - d)); }

static void tf2x32(uint32_t k0, uint32_t k1, uint32_t c0, uint32_t c1,
                   uint32_t& o0, uint32_t& o1) {
    const uint32_t ks[3] = { k0, k1, k0 ^ k1 ^ 0x1BD11BDAu };
    uint32_t x0 = c0 + ks[0];
    uint32_t x1 = c1 + ks[1];
    static const int R[8] = {13, 15, 26, 6, 17, 29, 16, 24};
    for (int s = 0; s < 5; ++s) {
        const int* r = R + (s % 2) * 4;
        for (int j = 0; j < 4; ++j) {
            x0 += x1;
            x1 = rotl32h(x1, r[j]);
            x1 ^= x0;
        }
        x0 += ks[(s + 1) % 3];
        x1 += ks[(s + 2) % 3] + (uint32_t)(s + 1);
    }
    o0 = x0; o1 = x1;
}

static PermTab build_tab() {
    PermTab t;
    for (int i = 0; i < SAMPLE_NUM; ++i) {
        uint32_t f0, f1;
        tf2x32(0u, 42u, 0u, (uint32_t)i, f0, f1);
        uint32_t s0, s1;
        tf2x32(f0, f1, 0u, 1u, s0, s1);
        uint32_t bits[32];
        for (int j = 0; j < 32; ++j) {
            uint32_t o0, o1;
            tf2x32(s0, s1, 0u, (uint32_t)j, o0, o1);
            bits[j] = o0 ^ o1;
        }
        int perm[32];
        for (int j = 0; j < 32; ++j) perm[j] = j;
        std::stable_sort(perm, perm + 32, [&](int x, int y) {
            return bits[x] < bits[y];
        });
        for (int q = 0; q < SUBSET; ++q) t.p[i][q] = (unsigned char)perm[q];
    }
    return t;
}

// ---------------------------------------------------------------------------
// Kernel 1: FPS. r8 restructure:
//  - 1024 threads x 16 points/thread (was 512x32): 4 waves/SIMD instead of 2,
//    doubling TLP over the serial post-barrier chain. Scan VALU per SIMD is
//    unchanged (numerics-locked).
//  - Wave-level argmax reduce via DPP (row_shr:1/2/4/8 + row_bcast:15/31 on
//    the u64 key, old-preserve bound_ctrl -- max(k,k)=k makes masked/invalid
//    lanes harmless). Replaces 12 serial ds_bpermute round-trips (~500 cyc
//    of DS latency) with ~30 low-latency VALU ops. Full-wave max lands in
//    lane 63, which writes the per-wave LDS slot.
//  - Cross-wave reduce: every lane reads skey[lane&15] (one broadcast
//    ds_read_b64 instead of 16 sequential reads), 4 row_shr DPP steps put
//    the block max in lane 15; readlane -> scalar winner index -> s_load of
//    winner coords (same as before).
// Numerics identical to passing rounds 3-7: contract(off), dist
// ((dx*dx+dy*dy)+dz*dz) RNE, fminf, strict-> ascending-index argmax,
// key = dist_bits<<32 | ~p (p = i*1024+tid now); the u64 key max is
// associative/commutative so any reduce schedule selects the identical
// winner. One barrier/iter; parity double-buffer keeps next iter's lane-63
// writes race-free. Coords stay pinned in VGPRs via empty asm (r7 lesson:
// the compiler otherwise rematerializes the loads inside the t-loop).
// ---------------------------------------------------------------------------
#define REP16(M) M(0) M(1) M(2) M(3) M(4) M(5) M(6) M(7) \
                 M(8) M(9) M(10) M(11) M(12) M(13) M(14) M(15)

// u64 max across lanes, one DPP step. old-preserve (bound_ctrl=false,
// masks 0xf): lanes with invalid source keep their own key -> max no-op.
// Both halves move with the same lane mapping, so lo/hi stay consistent.
#define DPP_MAX_STEP(var, ctrl) { \
        const unsigned lo_ = (unsigned)(var); \
        const unsigned hi_ = (unsigned)((var) >> 32); \
        const unsigned olo_ = (unsigned)__builtin_amdgcn_update_dpp( \
            (int)lo_, (int)lo_, (ctrl), 0xf, 0xf, false); \
        const unsigned ohi_ = (unsigned)__builtin_amdgcn_update_dpp( \
            (int)hi_, (int)hi_, (ctrl), 0xf, 0xf, false); \
        const unsigned long long o_ = \
            ((unsigned long long)ohi_ << 32) | (unsigned long long)olo_; \
        (var) = (o_ > (var)) ? o_ : (var); }

__global__ __launch_bounds__(1024, 4) void fps_kernel(const float* __restrict__ xyz,
                                                      float* __restrict__ centers,
                                                      float* __restrict__ sx) {
#pragma clang fp contract(off)
    const int b = blockIdx.x;
    const int tid = threadIdx.x;
    const int wv = tid >> 6;
    const int lane = tid & 63;

    __shared__ unsigned long long skey[2][16];

    const float* base = xyz + (size_t)b * NPTS * 3;

#define P_DECL(i) float px##i, py##i, pz##i, dd##i;
    REP16(P_DECL)
#undef P_DECL

#define P_LOAD(i) { \
        const int p = (i) * 1024 + tid; \
        px##i = base[p * 3 + 0]; \
        py##i = base[p * 3 + 1]; \
        pz##i = base[p * 3 + 2]; \
        dd##i = 1e10f; \
        sx[(size_t)b * NPTS + p] = (px##i * px##i + py##i * py##i) + pz##i * pz##i; }
    REP16(P_LOAD)
#undef P_LOAD

    // Pin coords to VGPRs: an asm def cannot be rematerialized, so the
    // compiler can no longer re-execute the global loads inside the t-loop.
#define P_PIN(i) asm volatile("" : "+v"(px##i), "+v"(py##i), "+v"(pz##i));
    REP16(P_PIN)
#undef P_PIN

    float cx = base[0], cy = base[1], cz = base[2];
    if (tid == 0) {
        float* dst = centers + (size_t)b * NPOINT * 3;
        dst[0] = cx; dst[1] = cy; dst[2] = cz;
    }
    __syncthreads();

    for (int t = 1; t < NPOINT; ++t) {
        const int par = t & 1;
        float bv = -1.0f;
        int bi = 0;
        // ascending i with strict > keeps the smallest index on ties,
        // matching numpy argmax first-index semantics (verified r3-r7).
#define P_SCAN(i) { \
        const float dx = px##i - cx; \
        const float dy = py##i - cy; \
        const float dz = pz##i - cz; \
        const float d = dx * dx + dy * dy + dz * dz; \
        const float nd = fminf(dd##i, d); \
        dd##i = nd; \
        if (nd > bv) { bv = nd; bi = (i); } }
        REP16(P_SCAN)
#undef P_SCAN

        const unsigned bp = ((unsigned)bi << 10) | (unsigned)tid;  // bi*1024+tid
        unsigned long long key =
            ((unsigned long long)__float_as_uint(bv) << 32) |
            (unsigned long long)(0xFFFFFFFFu - bp);

        // wave64 u64-max reduce, all in the VALU pipe (no LDS round trips):
        // row_shr 1/2/4/8 -> lane15 of each 16-row has the row max;
        // row_bcast:15 folds row k into row k+1; row_bcast:31 folds the
        // lower half into the upper -> lane 63 has the full-wave max.
        DPP_MAX_STEP(key, 0x111)   // row_shr:1
        DPP_MAX_STEP(key, 0x112)   // row_shr:2
        DPP_MAX_STEP(key, 0x114)   // row_shr:4
        DPP_MAX_STEP(key, 0x118)   // row_shr:8
        DPP_MAX_STEP(key, 0x142)   // row_bcast:15
        DPP_MAX_STEP(key, 0x143)   // row_bcast:31
        if (lane == 63) skey[par][wv] = key;
        __syncthreads();

        // block reduce: each lane reads one of the 16 wave keys (broadcast
        // pattern, conflict-free), 4 row_shr DPP steps put the max of
        // skey[0..15] into lane 15 of every row.
        unsigned long long kk = skey[par][lane & 15];
        DPP_MAX_STEP(kk, 0x111)
        DPP_MAX_STEP(kk, 0x112)
        DPP_MAX_STEP(kk, 0x114)
        DPP_MAX_STEP(kk, 0x118)

        const unsigned klo = (unsigned)__builtin_amdgcn_readlane((int)(unsigned)kk, 15);
        const int ps = __builtin_amdgcn_readfirstlane(
            (int)(0xFFFFFFFFu - klo));             // scalar winner index
        const float* sp = base + (size_t)ps * 3;
        cx = sp[0]; cy = sp[1]; cz = sp[2];        // scalar loads (L2-resident)

        if (tid == 0) {
            float* dst = centers + ((size_t)b * NPOINT + t) * 3;
            dst[0] = cx; dst[1] = cy; dst[2] = cz;
        }
    }
}

// ---------------------------------------------------------------------------
// Kernel 2: exact KNN top-32 (ascending d2, ties -> lower index), one block
// per center. Radix-select on the monotone uint key of
// d2 = (|c|^2 + |x|^2) - 2*dot (reference association, _rn ops), then exact
// O(L^2) rank of the candidate superset. Writes grouped coords rank-sorted.
// (unchanged from the passing round-3 kernel)
// ---------------------------------------------------------------------------
__global__ __launch_bounds__(256) void knn_kernel(const float* __restrict__ xyz,
                                                  const float* __restrict__ centers,
                                                  const float* __restrict__ sx,
                                                  float* __restrict__ grouped) {
    const int bs = blockIdx.x;
    const int b = bs >> 10;
    const int tid = threadIdx.x;

    __shared__ unsigned hist[2048];
    __shared__ unsigned ckey[CAP];
    __shared__ int cidx[CAP];
    __shared__ int cnt;
    __shared__ int bstar;

    const float cx = centers[(size_t)bs * 3 + 0];
    const float cy = centers[(size_t)bs * 3 + 1];
    const float cz = centers[(size_t)bs * 3 + 2];
    const float sc = __fadd_rn(__fadd_rn(__fmul_rn(cx, cx), __fmul_rn(cy, cy)),
                               __fmul_rn(cz, cz));

    for (int q = tid; q < 2048; q += 256) hist[q] = 0;
    if (tid == 0) cnt = 0;
    __syncthreads();

    const float* base = xyz + (size_t)b * NPTS * 3;
    const float* sxb = sx + (size_t)b * NPTS;

    for (int j = tid; j < NPTS; j += 256) {
        float xx = base[j * 3 + 0], xy = base[j * 3 + 1], xz = base[j * 3 + 2];
        float dot = __fadd_rn(__fadd_rn(__fmul_rn(cx, xx), __fmul_rn(cy, xy)),
                              __fmul_rn(cz, xz));
        float d2 = __fsub_rn(__fadd_rn(sc, sxb[j]), __fmul_rn(2.0f, dot));
        unsigned u = __float_as_uint(d2);
        unsigned key = u ^ ((u & 0x80000000u) ? 0xFFFFFFFFu : 0x80000000u);
        atomicAdd(&hist[key >> 21], 1u);
    }
    __syncthreads();

    if (tid < 64) {
        unsigned sum = 0;
#pragma unroll
        for (int q = 0; q < 32; ++q) sum += hist[tid * 32 + q];
        unsigned incl = sum;
        for (int d = 1; d < 64; d <<= 1) {
            unsigned o = __shfl_up(incl, d, 64);
            if (tid >= d) incl += o;
        }
        unsigned long long m = __ballot(incl >= 32u);
        int L = __ffsll(m) - 1;
        if (tid == L) {
            unsigned cum = incl - sum;
            int bb = L * 32 + 31;
            for (int q = 0; q < 32; ++q) {
                cum += hist[L * 32 + q];
                if (cum >= 32u) { bb = L * 32 + q; break; }
            }
            bstar = bb;
        }
    }
    __syncthreads();

    const int bst = bstar;
    for (int j = tid; j < NPTS; j += 256) {
        float xx = base[j * 3 + 0], xy = base[j * 3 + 1], xz = base[j * 3 + 2];
        float dot = __fadd_rn(__fadd_rn(__fmul_rn(cx, xx), __fmul_rn(cy, xy)),
                              __fmul_rn(cz, xz));
        float d2 = __fsub_rn(__fadd_rn(sc, sxb[j]), __fmul_rn(2.0f, dot));
        unsigned u = __float_as_uint(d2);
        unsigned key = u ^ ((u & 0x80000000u) ? 0xFFFFFFFFu : 0x80000000u);
        if ((int)(key >> 21) <= bst) {
            int pos = atomicAdd(&cnt, 1);
            if (pos < CAP) { ckey[pos] = key; cidx[pos] = j; }
        }
    }
    __syncthreads();

    const int L2 = min(cnt, CAP);
    for (int c = tid; c < L2; c += 256) {
        const unsigned k = ckey[c];
        const int id = cidx[c];
        int rank = 0;
        for (int m2 = 0; m2 < L2; ++m2) {
            const unsigned km = ckey[m2];
            rank += (km < k || (km == k && cidx[m2] < id)) ? 1 : 0;
        }
        if (rank < KNN) {
            float* dst = grouped + ((size_t)bs * KNN + rank) * 3;
            dst[0] = base[id * 3 + 0];
            dst[1] = base[id * 3 + 1];
            dst[2] = base[id * 3 + 2];
        }
    }
}

// ---------------------------------------------------------------------------
// Kernel 3: robust centroid + features, numpy f32 rounding (no fma; matching
// summation orders). (unchanged from the passing round-3 kernel)
// ---------------------------------------------------------------------------
__global__ __launch_bounds__(256) void feat_kernel(const float* __restrict__ centers,
                                                   const float* __restrict__ grouped,
                                                   float* __restrict__ out,
                                                   PermTab tab) {
    const int bs = blockIdx.x * 256 + threadIdx.x;
    if (bs >= BATCH * NPOINT) return;

    const float* g = grouped + (size_t)bs * KNN * 3;

    float clx[SAMPLE_NUM], cly[SAMPLE_NUM], clz[SAMPLE_NUM];
    for (int i = 0; i < SAMPLE_NUM; ++i) {
        float sxm = 0.f, sym = 0.f, szm = 0.f;
        for (int j = 0; j < SUBSET; ++j) {
            const int p = tab.p[i][j];
            sxm = __fadd_rn(sxm, g[p * 3 + 0]);
            sym = __fadd_rn(sym, g[p * 3 + 1]);
            szm = __fadd_rn(szm, g[p * 3 + 2]);
        }
        clx[i] = __fdiv_rn(sxm, 29.0f);
        cly[i] = __fdiv_rn(sym, 29.0f);
        clz[i] = __fdiv_rn(szm, 29.0f);
    }

    float sq[SAMPLE_NUM];
#pragma unroll
    for (int i = 0; i < SAMPLE_NUM; ++i)
        sq[i] = __fadd_rn(__fadd_rn(__fmul_rn(clx[i], clx[i]), __fmul_rn(cly[i], cly[i])),
                          __fmul_rn(clz[i], clz[i]));

    float ps[SAMPLE_NUM];
#pragma unroll
    for (int i = 0; i < SAMPLE_NUM; ++i) {
        float pd[SAMPLE_NUM];
#pragma unroll
        for (int j = 0; j < SAMPLE_NUM; ++j) {
            float dot = __fadd_rn(__fadd_rn(__fmul_rn(clx[i], clx[j]), __fmul_rn(cly[i], cly[j])),
                                  __fmul_rn(clz[i], clz[j]));
            pd[j] = __fsub_rn(__fadd_rn(sq[i], sq[j]), __fmul_rn(2.0f, dot));
        }
        float res = __fadd_rn(__fadd_rn(__fadd_rn(pd[0], pd[1]), __fadd_rn(pd[2], pd[3])),
                              __fadd_rn(__fadd_rn(pd[4], pd[5]), __fadd_rn(pd[6], pd[7])));
        res = __fadd_rn(res, pd[8]);
        res = __fadd_rn(res, pd[9]);
        ps[i] = res;
    }

    int rnk[SAMPLE_NUM];
#pragma unroll
    for (int j = 0; j < SAMPLE_NUM; ++j) {
        int r = 0;
#pragma unroll
        for (int m = 0; m < SAMPLE_NUM; ++m)
            r += (ps[m] < ps[j] || (ps[m] == ps[j] && m < j)) ? 1 : 0;
        rnk[j] = r;
    }

    float csx = 0.f, csy = 0.f, csz = 0.f;
    for (int r = 0; r < SELN; ++r) {
#pragma unroll
        for (int j = 0; j < SAMPLE_NUM; ++j) {
            if (rnk[j] == r) {
                csx = __fadd_rn(csx, clx[j]);
                csy = __fadd_rn(csy, cly[j]);
                csz = __fadd_rn(csz, clz[j]);
            }
        }
    }
    const float ccx = __fdiv_rn(csx, 7.0f);
    const float ccy = __fdiv_rn(csy, 7.0f);
    const float ccz = __fdiv_rn(csz, 7.0f);

    const float nx = centers[(size_t)bs * 3 + 0];
    const float ny = centers[(size_t)bs * 3 + 1];
    const float nz = centers[(size_t)bs * 3 + 2];

    const float ref_norm = __fsqrt_rn(__fadd_rn(
        __fadd_rn(__fmul_rn(nx, nx), __fmul_rn(ny, ny)), __fmul_rn(nz, nz)));
    const float den = __fadd_rn(ref_norm, 1e-4f);
    const float ux = __fdiv_rn(nx, den), uy = __fdiv_rn(ny, den), uz = __fdiv_rn(nz, den);
    const float ix = __fadd_rn(__fmul_rn(RADIUS, ux), nx);
    const float iy = __fadd_rn(__fmul_rn(RADIUS, uy), ny);
    const float iz = __fadd_rn(__fmul_rn(RADIUS, uz), nz);

    const float crvx = __fsub_rn(nx, ccx), crvy = __fsub_rn(ny, ccy), crvz = __fsub_rn(nz, ccz);
    const float crd = __fsqrt_rn(__fadd_rn(
        __fadd_rn(__fmul_rn(crvx, crvx), __fmul_rn(crvy, crvy)), __fmul_rn(crvz, crvz)));
    const float civx = __fsub_rn(ix, ccx), civy = __fsub_rn(iy, ccy), civz = __fsub_rn(iz, ccz);
    const float cid = __fsqrt_rn(__fadd_rn(
        __fadd_rn(__fmul_rn(civx, civx), __fmul_rn(civy, civy)), __fmul_rn(civz, civz)));
    const float dot = __fadd_rn(__fadd_rn(__fmul_rn(crvx, civx), __fmul_rn(crvy, civy)),
                                __fmul_rn(crvz, civz));
    const float ang_rci = __fdiv_rn(dot, __fadd_rn(__fmul_rn(crd, cid), 1e-6f));

    const float irvx = __fsub_rn(nx, ix), irvy = __fsub_rn(ny, iy), irvz = __fsub_rn(nz, iz);
    const float icvx = __fsub_rn(ccx, ix), icvy = __fsub_rn(ccy, iy), icvz = __fsub_rn(ccz, iz);
    const float dot2 = __fadd_rn(__fadd_rn(__fmul_rn(irvx, icvx), __fmul_rn(irvy, icvy)),
                                 __fmul_rn(irvz, icvz));
    const float ang_ric = __fdiv_rn(dot2, __fadd_rn(__fmul_rn(RADIUS, cid), 1e-6f));

    float* o = out + (size_t)bs * 5;
    o[0] = ref_norm;
    o[1] = crd;
    o[2] = cid;
    o[3] = ang_rci;
    o[4] = ang_ric;
}

// ---------------------------------------------------------------------------
extern "C" void kernel_launch(void* const* d_in, const int* in_sizes, int n_in,
                              void* d_out, int out_size, void* d_ws, size_t ws_size,
                              hipStream_t stream) {
    const float* xyz = (const float*)d_in[0];
    float* out = (float*)d_out;

    float* centers = (float*)d_ws;                       // B*NPOINT*3
    float* sx = centers + (size_t)BATCH * NPOINT * 3;    // B*N
    float* grouped = sx + (size_t)BATCH * NPTS;          // B*NPOINT*K*3

    static PermTab tab = build_tab();  // deterministic, host-only

    fps_kernel<<<BATCH, 1024, 0, stream>>>(xyz, centers, sx);
    knn_kernel<<<BATCH * NPOINT, 256, 0, stream>>>(xyz, centers, sx, grouped);
    feat_kernel<<<(BATCH * NPOINT + 255) / 256, 256, 0, stream>>>(centers, grouped, out, tab);
}